// Round 1
// baseline (3001.452 us; speedup 1.0000x reference)
//
#include <hip/hip_runtime.h>
#include <math.h>

#define D_DIM 128   // D
#define TWO_D 256
#define HC    512   // H*C
#define NH    4     // heads

// ---- ordered-uint encoding of float for atomicMax ----
__device__ __forceinline__ unsigned ford(float f){
    unsigned u = __float_as_uint(f);
    return (u & 0x80000000u) ? ~u : (u | 0x80000000u);
}
__device__ __forceinline__ float funord(unsigned e){
    unsigned u = (e & 0x80000000u) ? (e ^ 0x80000000u) : ~e;
    return __uint_as_float(u);
}

// init out with final bias; zero node_max (ordered -inf-ish) and node_sum
__global__ void k_init(float* __restrict__ out, const float* __restrict__ bias,
                       unsigned* __restrict__ node_max, float* __restrict__ node_sum, int N){
    long total = (long)N * HC;
    long stride = (long)gridDim.x * blockDim.x;
    for (long i = (long)blockIdx.x * blockDim.x + threadIdx.x; i < total; i += stride){
        out[i] = bias[i & (HC-1)];
        if (i < (long)N * NH){ node_max[i] = 0u; node_sum[i] = 0.f; }
    }
}

// x[n, :] = embs[n, :] @ W_l + b_l      (M=N, N=512, K=128), 8 nodes per block
__global__ __launch_bounds__(256) void k_x(const float* __restrict__ embs,
                                           const float* __restrict__ W_l,
                                           const float* __restrict__ b_l,
                                           float* __restrict__ x, int N){
    const int m0 = blockIdx.x * 8;
    const int tid = threadIdx.x;
    __shared__ float smA[8][D_DIM];
    for (int i = tid; i < 8 * D_DIM; i += 256){
        int m = i >> 7, k = i & 127;
        int node = m0 + m;
        smA[m][k] = (node < N) ? embs[(long)node * D_DIM + k] : 0.f;
    }
    __syncthreads();
    float acc[8][2] = {};
    const float* wp = W_l + tid;
    for (int k = 0; k < D_DIM; k++){
        float w0 = wp[(long)k * HC];
        float w1 = wp[(long)k * HC + 256];
        #pragma unroll
        for (int m = 0; m < 8; m++){
            float a_ = smA[m][k];
            acc[m][0] += a_ * w0;
            acc[m][1] += a_ * w1;
        }
    }
    float b0 = b_l[tid], b1 = b_l[tid + 256];
    #pragma unroll
    for (int m = 0; m < 8; m++){
        int node = m0 + m;
        if (node >= N) break;
        x[(long)node * HC + tid]       = acc[m][0] + b0;
        x[(long)node * HC + tid + 256] = acc[m][1] + b1;
    }
}

// Per-edge fused: edge_attr = gelu([e_src|e_trg] @ rel[r]); e_p = edge_attr @ W_e;
// z = lrelu(x_i + x_j + e_p); logits[e,h] = z . att[h];  atomicMax into node_max.
__global__ __launch_bounds__(256) void k_edge(const float* __restrict__ embs,
                                              const int* __restrict__ src,
                                              const int* __restrict__ trg,
                                              const int* __restrict__ etype,
                                              const float* __restrict__ rel,   // [R,256,128]
                                              const float* __restrict__ W_e,   // [128,512]
                                              const float* __restrict__ att,   // [512] flat
                                              const float* __restrict__ x,     // [N,512]
                                              float* __restrict__ logits,      // [E,4]
                                              unsigned* __restrict__ node_max, // [N,4]
                                              int E){
    const int e = blockIdx.x;
    if (e >= E) return;
    const int tid = threadIdx.x;
    const int s = src[e], t = trg[e], r = etype[e];

    __shared__ float sm_e[TWO_D];     // concat(embs[s], embs[t])
    __shared__ float sm_t[D_DIM];     // edge_attr (post-gelu)
    __shared__ float sm_part[HC];     // scratch: split-K partials, then per-col logit partials

    if (tid < 128) sm_e[tid] = embs[(long)s * D_DIM + tid];
    else           sm_e[tid] = embs[(long)t * D_DIM + (tid - 128)];
    __syncthreads();

    // phase 1: t[j] = sum_k e_emb[k] * rel[r][k][j], split-K by 2
    {
        int j = tid & 127;
        int half = tid >> 7;
        const float* rp = rel + ((long)r * TWO_D + half * 128) * D_DIM + j;
        const float* ep = sm_e + half * 128;
        float acc = 0.f;
        #pragma unroll 8
        for (int k = 0; k < 128; k++) acc += ep[k] * rp[(long)k * D_DIM];
        sm_part[tid] = acc;
        __syncthreads();
        if (tid < 128){
            float v = sm_part[tid] + sm_part[tid + 128];
            // exact GELU (erf form)
            sm_t[tid] = 0.5f * v * (1.f + erff(v * 0.70710678118654752f));
        }
        __syncthreads();
    }

    // phase 2: cols c = tid, tid+256. ep = edge_attr @ W_e[:,c]; z = lrelu(xi+xj+ep); part = z*att[c]
    float part[2];
    #pragma unroll
    for (int u = 0; u < 2; u++){
        int c = tid + u * 256;
        const float* wp = W_e + c;
        float acc = 0.f;
        #pragma unroll 8
        for (int k = 0; k < 128; k++) acc += sm_t[k] * wp[(long)k * HC];
        float z = x[(long)t * HC + c] + x[(long)s * HC + c] + acc;
        z = (z > 0.f) ? z : 0.2f * z;
        part[u] = z * att[c];
    }
    sm_part[tid]       = part[0];
    sm_part[tid + 256] = part[1];
    __syncthreads();

    // reduce 128 cols per head; wave w handles head w
    int w = tid >> 6, lane = tid & 63;
    float v = sm_part[w * 128 + lane] + sm_part[w * 128 + 64 + lane];
    #pragma unroll
    for (int off = 32; off > 0; off >>= 1) v += __shfl_down(v, off, 64);
    if (lane == 0){
        logits[(long)e * NH + w] = v;
        atomicMax(&node_max[(long)t * NH + w], ford(v));
    }
}

// ex = exp(logit - m[trg]); store in place; atomicAdd into node_sum
__global__ void k_softmax(float* __restrict__ logits, const int* __restrict__ trg,
                          const unsigned* __restrict__ node_max, float* __restrict__ node_sum,
                          int E){
    long total = (long)E * NH;
    long i = (long)blockIdx.x * blockDim.x + threadIdx.x;
    if (i >= total) return;
    int e = (int)(i >> 2), h = (int)(i & 3);
    int t = trg[e];
    float m = funord(node_max[(long)t * NH + h]);
    float ex = expf(logits[i] - m);
    logits[i] = ex;
    atomicAdd(&node_sum[(long)t * NH + h], ex);
}

// out[trg] += x[src] * alpha  (alpha = ex / max(sum,1e-16)), one block of 128 per edge
__global__ __launch_bounds__(128) void k_agg(const float* __restrict__ ex,      // [E,4]
                                             const float* __restrict__ node_sum,// [N,4]
                                             const float* __restrict__ x,       // [N,512]
                                             const int* __restrict__ src,
                                             const int* __restrict__ trg,
                                             float* __restrict__ out, int E){
    const int e = blockIdx.x;
    if (e >= E) return;
    const int tid = threadIdx.x;
    const int s = src[e], t = trg[e];
    __shared__ float a[NH];
    if (tid < NH){
        float sum = node_sum[(long)t * NH + tid];
        a[tid] = ex[(long)e * NH + tid] / fmaxf(sum, 1e-16f);
    }
    __syncthreads();
    #pragma unroll
    for (int u = 0; u < 4; u++){
        int c = tid + u * 128;
        atomicAdd(&out[(long)t * HC + c], x[(long)s * HC + c] * a[c >> 7]);
    }
}

extern "C" void kernel_launch(void* const* d_in, const int* in_sizes, int n_in,
                              void* d_out, int out_size, void* d_ws, size_t ws_size,
                              hipStream_t stream) {
    const float* embs       = (const float*)d_in[0];
    const int*   edge_index = (const int*)  d_in[1];
    const int*   etype      = (const int*)  d_in[2];
    const float* rel        = (const float*)d_in[3];
    const float* W_l        = (const float*)d_in[4];
    const float* b_l        = (const float*)d_in[5];
    const float* W_e        = (const float*)d_in[6];
    const float* att        = (const float*)d_in[7];
    const float* bias       = (const float*)d_in[8];

    const int N = in_sizes[0] / D_DIM;
    const int E = in_sizes[1] / 2;
    const int* src = edge_index;
    const int* trg = edge_index + E;

    char* ws = (char*)d_ws;
    size_t off = 0;
    float* x = (float*)(ws + off);           off += (size_t)N * HC * sizeof(float);
    float* logits = (float*)(ws + off);      off += (size_t)E * NH * sizeof(float);
    unsigned* node_max = (unsigned*)(ws + off); off += (size_t)N * NH * sizeof(unsigned);
    float* node_sum = (float*)(ws + off);    off += (size_t)N * NH * sizeof(float);

    float* out = (float*)d_out;

    k_init<<<2048, 256, 0, stream>>>(out, bias, node_max, node_sum, N);
    k_x<<<(N + 7) / 8, 256, 0, stream>>>(embs, W_l, b_l, x, N);
    k_edge<<<E, 256, 0, stream>>>(embs, src, trg, etype, rel, W_e, att, x, logits, node_max, E);
    k_softmax<<<(int)(((long)E * NH + 255) / 256), 256, 0, stream>>>(logits, trg, node_max, node_sum, E);
    k_agg<<<E, 128, 0, stream>>>(logits, node_sum, x, src, trg, out, E);
}

// Round 3
// 1239.603 us; speedup vs baseline: 2.4213x; 2.4213x over previous
//
#include <hip/hip_runtime.h>
#include <math.h>

#define D_DIM 128
#define TWO_D 256
#define HC    512
#define NH    4
#define RNUM  8
#define BM    128
#define BK    32

// meta layout (ints): [0..7]=cnt, [8..16]=offsets, [17..25]=blk_start, [26..33]=cursor
#define M_CNT 0
#define M_OFF 8
#define M_BLK 17
#define M_CUR 26

__device__ __forceinline__ unsigned ford(float f){
    unsigned u = __float_as_uint(f);
    return (u & 0x80000000u) ? ~u : (u | 0x80000000u);
}
__device__ __forceinline__ float funord(unsigned e){
    unsigned u = (e & 0x80000000u) ? (e ^ 0x80000000u) : ~e;
    return __uint_as_float(u);
}
__device__ __forceinline__ float bf2f(unsigned short v){
    return __uint_as_float(((unsigned)v) << 16);
}
__device__ __forceinline__ unsigned short f2bf(float f){
    unsigned u = __float_as_uint(f);
    u += 0x7fffu + ((u >> 16) & 1u);   // round-to-nearest-even
    return (unsigned short)(u >> 16);
}

// ---------------- init: out=bias, node_max/node_sum=0, meta cnt=0 ----------------
__global__ void k_init(float* __restrict__ out, const float* __restrict__ bias,
                       unsigned* __restrict__ node_max, float* __restrict__ node_sum,
                       int* __restrict__ meta, int N){
    long total = (long)N * HC;
    long stride = (long)gridDim.x * blockDim.x;
    for (long i = (long)blockIdx.x * blockDim.x + threadIdx.x; i < total; i += stride){
        out[i] = bias[i & (HC-1)];
        if (i < (long)N * NH){ node_max[i] = 0u; node_sum[i] = 0.f; }
        if (i < RNUM) meta[M_CNT + i] = 0;
    }
}

// ---------------- bucketing ----------------
__global__ void k_hist(const int* __restrict__ etype, int* __restrict__ meta, int E){
    __shared__ int h[RNUM];
    int tid = threadIdx.x;
    if (tid < RNUM) h[tid] = 0;
    __syncthreads();
    int e = blockIdx.x * 256 + tid;
    if (e < E) atomicAdd(&h[etype[e]], 1);
    __syncthreads();
    if (tid < RNUM) atomicAdd(&meta[M_CNT + tid], h[tid]);
}

__global__ void k_offsets(int* __restrict__ meta){
    if (threadIdx.x == 0 && blockIdx.x == 0){
        int off = 0, blk = 0;
        meta[M_OFF] = 0; meta[M_BLK] = 0;
        for (int r = 0; r < RNUM; r++){
            int c = meta[M_CNT + r];
            off += c; blk += (c + BM - 1) / BM;
            meta[M_OFF + r + 1] = off;
            meta[M_BLK + r + 1] = blk;
            meta[M_CUR + r] = 0;
        }
    }
}

__global__ void k_scatter(const int* __restrict__ etype, int* __restrict__ meta,
                          int* __restrict__ perm, int E){
    __shared__ int lcnt[RNUM], lbase[RNUM];
    int tid = threadIdx.x;
    if (tid < RNUM) lcnt[tid] = 0;
    __syncthreads();
    int e = blockIdx.x * 256 + tid;
    int r = 0, rank = 0;
    if (e < E){ r = etype[e]; rank = atomicAdd(&lcnt[r], 1); }
    __syncthreads();
    if (tid < RNUM) lbase[tid] = atomicAdd(&meta[M_CUR + tid], lcnt[tid]);
    __syncthreads();
    if (e < E) perm[meta[M_OFF + r] + lbase[r] + rank] = e;
}

// ---------------- x = embs @ W_l + b_l ----------------
__global__ __launch_bounds__(256) void k_x(const float* __restrict__ embs,
                                           const float* __restrict__ W_l,
                                           const float* __restrict__ b_l,
                                           float* __restrict__ x, int N){
    const int m0 = blockIdx.x * 8;
    const int tid = threadIdx.x;
    __shared__ float smA[8][D_DIM];
    for (int i = tid; i < 8 * D_DIM; i += 256){
        int m = i >> 7, k = i & 127;
        int node = m0 + m;
        smA[m][k] = (node < N) ? embs[(long)node * D_DIM + k] : 0.f;
    }
    __syncthreads();
    float acc[8][2] = {};
    const float* wp = W_l + tid;
    for (int k = 0; k < D_DIM; k++){
        float w0 = wp[(long)k * HC];
        float w1 = wp[(long)k * HC + 256];
        #pragma unroll
        for (int m = 0; m < 8; m++){
            float a_ = smA[m][k];
            acc[m][0] += a_ * w0;
            acc[m][1] += a_ * w1;
        }
    }
    float b0 = b_l[tid], b1 = b_l[tid + 256];
    #pragma unroll
    for (int m = 0; m < 8; m++){
        int node = m0 + m;
        if (node >= N) break;
        x[(long)node * HC + tid]       = acc[m][0] + b0;
        x[(long)node * HC + tid + 256] = acc[m][1] + b1;
    }
}

// ---------------- edge_attr = gelu(concat(embs[s],embs[t]) @ rel[r]) ----------------
// one block = up to 128 edges of a single relation; tiled GEMM [128,256]@[256,128]
__global__ __launch_bounds__(256, 2) void k_attr(
    const float* __restrict__ embs, const int* __restrict__ src, const int* __restrict__ trg,
    const float* __restrict__ rel, const int* __restrict__ perm, const int* __restrict__ meta,
    unsigned short* __restrict__ edge_attr)
{
    __shared__ float sAt[BK][BM + 4];   // [kk][row]  (transposed A chunk)
    __shared__ float sB[BK][D_DIM + 4]; // [kk][j]
    __shared__ int s_eid[BM], s_s[BM], s_t[BM];
    __shared__ int s_meta[3];

    const int tid = threadIdx.x;
    const int b = blockIdx.x;
    if (tid == 0){
        int nblk = meta[M_BLK + RNUM];
        if (b >= nblk){ s_meta[0] = -1; }
        else {
            int r = 0;
            while (b >= meta[M_BLK + r + 1]) r++;
            int chunk = b - meta[M_BLK + r];
            int base = meta[M_OFF + r] + chunk * BM;
            s_meta[0] = r; s_meta[1] = base;
            s_meta[2] = min(BM, meta[M_OFF + r + 1] - base);
        }
    }
    __syncthreads();
    const int r = s_meta[0];
    if (r < 0) return;
    const int base = s_meta[1], cnt = s_meta[2];

    if (tid < BM){
        int e = perm[base + min(tid, cnt - 1)];
        s_eid[tid] = e; s_s[tid] = src[e]; s_t[tid] = trg[e];
    }
    __syncthreads();

    float acc[8][8] = {};
    const int ty = tid >> 4, tx = tid & 15;
    const int r0 = ty * 8, c0 = tx * 8;

    for (int c = 0; c < 8; c++){
        const int kbase = (c & 3) * BK;
        const int* nodes = (c < 4) ? s_s : s_t;
        {   // stage A transposed: 128 rows x 32 k
            int row = tid >> 3;
            int kk = (tid & 7) * 4;
            for (int rr = row; rr < BM; rr += 32){
                const float4 v = *(const float4*)&embs[(long)nodes[rr] * D_DIM + kbase + kk];
                sAt[kk + 0][rr] = v.x; sAt[kk + 1][rr] = v.y;
                sAt[kk + 2][rr] = v.z; sAt[kk + 3][rr] = v.w;
            }
        }
        {   // stage B: rel[r][c*32 + kk][j]
            int kk = tid >> 5;
            int j = (tid & 31) * 4;
            const float* bp = rel + ((long)r * TWO_D + c * BK) * D_DIM;
            for (int k2 = kk; k2 < BK; k2 += 8)
                *(float4*)&sB[k2][j] = *(const float4*)&bp[(long)k2 * D_DIM + j];
        }
        __syncthreads();
        #pragma unroll
        for (int kk = 0; kk < BK; kk++){
            float4 a0 = *(const float4*)&sAt[kk][r0];
            float4 a1 = *(const float4*)&sAt[kk][r0 + 4];
            float4 b0 = *(const float4*)&sB[kk][c0];
            float4 b1 = *(const float4*)&sB[kk][c0 + 4];
            float av[8] = {a0.x, a0.y, a0.z, a0.w, a1.x, a1.y, a1.z, a1.w};
            float bv[8] = {b0.x, b0.y, b0.z, b0.w, b1.x, b1.y, b1.z, b1.w};
            #pragma unroll
            for (int i = 0; i < 8; i++)
                #pragma unroll
                for (int u = 0; u < 8; u++)
                    acc[i][u] += av[i] * bv[u];
        }
        __syncthreads();
    }
    #pragma unroll
    for (int i = 0; i < 8; i++){
        int row = r0 + i;
        if (row < cnt){
            long p = (long)s_eid[row] * D_DIM + c0;
            union { uint4 u4; unsigned short h[8]; } pk;
            #pragma unroll
            for (int u = 0; u < 8; u++){
                float v = acc[i][u];
                v = 0.5f * v * (1.f + erff(v * 0.70710678118654752f));
                pk.h[u] = f2bf(v);
            }
            *(uint4*)&edge_attr[p] = pk.u4;
        }
    }
}

// ---------------- logits: z=lrelu(x_i+x_j+edge_attr@W_e); logits=z.att ----------------
// block = 128 edges x 1 head (128 cols); K=128
__global__ __launch_bounds__(256, 2) void k_logits(
    const unsigned short* __restrict__ edge_attr,
    const float* __restrict__ W_e, const float* __restrict__ att,
    const float* __restrict__ x, const int* __restrict__ src, const int* __restrict__ trg,
    float* __restrict__ logits, unsigned* __restrict__ node_max, int E)
{
    __shared__ float sAt[BK][BM + 4];
    __shared__ float sB[BK][D_DIM + 4];
    __shared__ float sred[BM][17];
    __shared__ int s_s[BM], s_t[BM];
    __shared__ float s_att[D_DIM];

    const int tid = threadIdx.x;
    const int e0 = blockIdx.x * BM;
    const int h = blockIdx.y;
    const int cnt = min(BM, E - e0);

    if (tid < BM){
        int e = e0 + min(tid, cnt - 1);
        s_s[tid] = src[e]; s_t[tid] = trg[e];
    }
    if (tid < D_DIM) s_att[tid] = att[h * D_DIM + tid];

    float acc[8][8] = {};
    const int ty = tid >> 4, tx = tid & 15;
    const int r0 = ty * 8, c0 = tx * 8;

    for (int c = 0; c < 4; c++){
        const int kbase = c * BK;
        {   // stage A (bf16 -> f32, transposed)
            int row = tid >> 3;
            int kk = (tid & 7) * 4;
            for (int rr = row; rr < BM; rr += 32){
                int e = e0 + min(rr, cnt - 1);
                const ushort4 v = *(const ushort4*)&edge_attr[(long)e * D_DIM + kbase + kk];
                sAt[kk + 0][rr] = bf2f(v.x); sAt[kk + 1][rr] = bf2f(v.y);
                sAt[kk + 2][rr] = bf2f(v.z); sAt[kk + 3][rr] = bf2f(v.w);
            }
        }
        {   // stage B: W_e[(kbase+kk)][h*128 + j]
            int kk = tid >> 5;
            int j = (tid & 31) * 4;
            const float* bp = W_e + (long)kbase * HC + h * D_DIM;
            for (int k2 = kk; k2 < BK; k2 += 8)
                *(float4*)&sB[k2][j] = *(const float4*)&bp[(long)k2 * HC + j];
        }
        __syncthreads();
        #pragma unroll
        for (int kk = 0; kk < BK; kk++){
            float4 a0 = *(const float4*)&sAt[kk][r0];
            float4 a1 = *(const float4*)&sAt[kk][r0 + 4];
            float4 b0 = *(const float4*)&sB[kk][c0];
            float4 b1 = *(const float4*)&sB[kk][c0 + 4];
            float av[8] = {a0.x, a0.y, a0.z, a0.w, a1.x, a1.y, a1.z, a1.w};
            float bv[8] = {b0.x, b0.y, b0.z, b0.w, b1.x, b1.y, b1.z, b1.w};
            #pragma unroll
            for (int i = 0; i < 8; i++)
                #pragma unroll
                for (int u = 0; u < 8; u++)
                    acc[i][u] += av[i] * bv[u];
        }
        __syncthreads();
    }

    // epilogue: z = lrelu(acc + x_i + x_j); partial att-dot per row
    float part[8];
    #pragma unroll
    for (int i = 0; i < 8; i++){
        int row = r0 + i;
        int s = s_s[row], t = s_t[row];
        long pi = (long)t * HC + h * D_DIM + c0;
        long pj = (long)s * HC + h * D_DIM + c0;
        float4 xi0 = *(const float4*)&x[pi];
        float4 xi1 = *(const float4*)&x[pi + 4];
        float4 xj0 = *(const float4*)&x[pj];
        float4 xj1 = *(const float4*)&x[pj + 4];
        float xiv[8] = {xi0.x, xi0.y, xi0.z, xi0.w, xi1.x, xi1.y, xi1.z, xi1.w};
        float xjv[8] = {xj0.x, xj0.y, xj0.z, xj0.w, xj1.x, xj1.y, xj1.z, xj1.w};
        float p = 0.f;
        #pragma unroll
        for (int u = 0; u < 8; u++){
            float z = acc[i][u] + xiv[u] + xjv[u];
            z = (z > 0.f) ? z : 0.2f * z;
            p += z * s_att[c0 + u];
        }
        part[i] = p;
    }
    #pragma unroll
    for (int i = 0; i < 8; i++) sred[r0 + i][tx] = part[i];
    __syncthreads();
    if (tid < cnt){
        float v = 0.f;
        #pragma unroll
        for (int q = 0; q < 16; q++) v += sred[tid][q];
        logits[(long)(e0 + tid) * NH + h] = v;
        atomicMax(&node_max[(long)s_t[tid] * NH + h], ford(v));
    }
}

// ---------------- softmax normalize pieces ----------------
__global__ void k_softmax(float* __restrict__ logits, const int* __restrict__ trg,
                          const unsigned* __restrict__ node_max, float* __restrict__ node_sum,
                          int E){
    long total = (long)E * NH;
    long i = (long)blockIdx.x * blockDim.x + threadIdx.x;
    if (i >= total) return;
    int e = (int)(i >> 2), hh = (int)(i & 3);
    int t = trg[e];
    float m = funord(node_max[(long)t * NH + hh]);
    float ex = expf(logits[i] - m);
    logits[i] = ex;
    atomicAdd(&node_sum[(long)t * NH + hh], ex);
}

// ---------------- out[trg] += x[src] * alpha ----------------
__global__ __launch_bounds__(128) void k_agg(const float* __restrict__ ex,
                                             const float* __restrict__ node_sum,
                                             const float* __restrict__ x,
                                             const int* __restrict__ src,
                                             const int* __restrict__ trg,
                                             float* __restrict__ out, int E){
    const int e = blockIdx.x;
    if (e >= E) return;
    const int tid = threadIdx.x;
    const int s = src[e], t = trg[e];
    __shared__ float a[NH];
    if (tid < NH){
        float sum = node_sum[(long)t * NH + tid];
        a[tid] = ex[(long)e * NH + tid] / fmaxf(sum, 1e-16f);
    }
    __syncthreads();
    #pragma unroll
    for (int u = 0; u < 4; u++){
        int c = tid + u * 128;
        atomicAdd(&out[(long)t * HC + c], x[(long)s * HC + c] * a[c >> 7]);
    }
}

extern "C" void kernel_launch(void* const* d_in, const int* in_sizes, int n_in,
                              void* d_out, int out_size, void* d_ws, size_t ws_size,
                              hipStream_t stream) {
    const float* embs       = (const float*)d_in[0];
    const int*   edge_index = (const int*)  d_in[1];
    const int*   etype      = (const int*)  d_in[2];
    const float* rel        = (const float*)d_in[3];
    const float* W_l        = (const float*)d_in[4];
    const float* b_l        = (const float*)d_in[5];
    const float* W_e        = (const float*)d_in[6];
    const float* att        = (const float*)d_in[7];
    const float* bias       = (const float*)d_in[8];

    const int N = in_sizes[0] / D_DIM;
    const int E = in_sizes[1] / 2;
    const int* src = edge_index;
    const int* trg = edge_index + E;

    char* ws = (char*)d_ws;
    size_t off = 0;
    float* x = (float*)(ws + off);                 off += (size_t)N * HC * sizeof(float);
    unsigned short* edge_attr = (unsigned short*)(ws + off); off += (size_t)E * D_DIM * sizeof(unsigned short);
    float* logits = (float*)(ws + off);            off += (size_t)E * NH * sizeof(float);
    unsigned* node_max = (unsigned*)(ws + off);    off += (size_t)N * NH * sizeof(unsigned);
    float* node_sum = (float*)(ws + off);          off += (size_t)N * NH * sizeof(float);
    int* perm = (int*)(ws + off);                  off += (size_t)E * sizeof(int);
    int* meta = (int*)(ws + off);                  off += 64 * sizeof(int);

    float* out = (float*)d_out;

    const int eb = (E + 255) / 256;
    const int ab = (E + BM - 1) / BM + RNUM;   // upper bound on per-relation chunk blocks
    const int lb = (E + BM - 1) / BM;

    k_init<<<2048, 256, 0, stream>>>(out, bias, node_max, node_sum, meta, N);
    k_hist<<<eb, 256, 0, stream>>>(etype, meta, E);
    k_offsets<<<1, 64, 0, stream>>>(meta);
    k_scatter<<<eb, 256, 0, stream>>>(etype, meta, perm, E);
    k_x<<<(N + 7) / 8, 256, 0, stream>>>(embs, W_l, b_l, x, N);
    k_attr<<<ab, 256, 0, stream>>>(embs, src, trg, rel, perm, meta, edge_attr);
    k_logits<<<dim3(lb, NH), 256, 0, stream>>>(edge_attr, W_e, att, x, src, trg, logits, node_max, E);
    k_softmax<<<(int)(((long)E * NH + 255) / 256), 256, 0, stream>>>(logits, trg, node_max, node_sum, E);
    k_agg<<<E, 128, 0, stream>>>(logits, node_sum, x, src, trg, out, E);
}

// Round 4
// 713.644 us; speedup vs baseline: 4.2058x; 1.7370x over previous
//
#include <hip/hip_runtime.h>
#include <math.h>

#define D_DIM 128
#define TWO_D 256
#define HC    512
#define NH    4
#define RNUM  8
#define BM    128

#define M_CNT 0
#define M_OFF 8
#define M_BLK 17
#define M_CUR 26

typedef __attribute__((ext_vector_type(8))) short v8s;       // 8 bf16 payload (MFMA A/B frag)
typedef __attribute__((ext_vector_type(4))) float v4f;       // MFMA C/D frag
typedef __attribute__((ext_vector_type(8))) unsigned short us8;

#define MFMA(a,b,c) __builtin_amdgcn_mfma_f32_16x16x32_bf16((a),(b),(c),0,0,0)

__device__ __forceinline__ unsigned ford(float f){
    unsigned u = __float_as_uint(f);
    return (u & 0x80000000u) ? ~u : (u | 0x80000000u);
}
__device__ __forceinline__ float funord(unsigned e){
    unsigned u = (e & 0x80000000u) ? (e ^ 0x80000000u) : ~e;
    return __uint_as_float(u);
}
__device__ __forceinline__ float bf2f(unsigned short v){
    return __uint_as_float(((unsigned)v) << 16);
}
__device__ __forceinline__ unsigned short f2bf(float f){
    unsigned u = __float_as_uint(f);
    u += 0x7fffu + ((u >> 16) & 1u);
    return (unsigned short)(u >> 16);
}

// ---- LDS swizzled tile helpers: 128 rows x 64 bf16, 16B-chunk XOR swizzle ----
// elem (r,k): chunk=(k>>3)^(r&7) ; frag reads are 2-way-conflict max (free).
__device__ __forceinline__ unsigned short* tile_ptr(unsigned short* buf, int r, int chunk){
    return buf + r * 64 + ((chunk ^ (r & 7)) << 3);
}
__device__ __forceinline__ v8s frag_ld(const unsigned short* buf, int r, int chunk){
    return *(const v8s*)(buf + r * 64 + ((chunk ^ (r & 7)) << 3));
}
// stage 128 rows x 64 bf16 (2 threads/row, 4x16B each) from per-row global base
__device__ __forceinline__ void stage64(unsigned short* lds, const unsigned short* gbase,
                                        long roff /*elements*/, int tid){
    int r = tid >> 1, p = tid & 1;
    const unsigned short* src = gbase + roff + p * 32;
    #pragma unroll
    for (int i = 0; i < 4; i++){
        int c = p * 4 + i;
        uint4 v = *(const uint4*)(src + i * 8);
        *(uint4*)tile_ptr(lds, r, c) = v;
    }
}

// ---------------- init ----------------
__global__ void k_init(float* __restrict__ out, const float* __restrict__ bias,
                       unsigned* __restrict__ node_max, float* __restrict__ node_sum,
                       int* __restrict__ meta, int N){
    long total = (long)N * HC;
    long stride = (long)gridDim.x * blockDim.x;
    for (long i = (long)blockIdx.x * blockDim.x + threadIdx.x; i < total; i += stride){
        out[i] = bias[i & (HC-1)];
        if (i < (long)N * NH){ node_max[i] = 0u; node_sum[i] = 0.f; }
        if (i < RNUM) meta[M_CNT + i] = 0;
    }
}

// ---------------- prep: bf16 conversions + B-operand transposes ----------------
// embs_bf[N][128]; rel_t[8][128n][256k]; W_e_t[512n][128k]; W_l_t[512n][128k]
__global__ void k_prep(const float* __restrict__ embs, const float* __restrict__ rel,
                       const float* __restrict__ W_e, const float* __restrict__ W_l,
                       unsigned short* __restrict__ embs_bf, unsigned short* __restrict__ rel_t,
                       unsigned short* __restrict__ W_e_t, unsigned short* __restrict__ W_l_t, int N){
    const long T0 = (long)N * D_DIM;
    const long T1 = T0 + (long)RNUM * D_DIM * TWO_D;
    const long T2 = T1 + (long)HC * D_DIM;
    const long T3 = T2 + (long)HC * D_DIM;
    long stride = (long)gridDim.x * blockDim.x;
    for (long i = (long)blockIdx.x * blockDim.x + threadIdx.x; i < T3; i += stride){
        if (i < T0){
            embs_bf[i] = f2bf(embs[i]);
        } else if (i < T1){
            long j = i - T0;
            int r = (int)(j >> 15);              // 128*256
            int rem = (int)(j & 32767);
            int n = rem >> 8, k = rem & 255;
            rel_t[j] = f2bf(rel[(long)r * 32768 + (long)k * D_DIM + n]);
        } else if (i < T2){
            long j = i - T1;
            int n = (int)(j >> 7), k = (int)(j & 127);
            W_e_t[j] = f2bf(W_e[(long)k * HC + n]);
        } else {
            long j = i - T2;
            int n = (int)(j >> 7), k = (int)(j & 127);
            W_l_t[j] = f2bf(W_l[(long)k * HC + n]);
        }
    }
}

// ---------------- bucketing ----------------
__global__ void k_hist(const int* __restrict__ etype, int* __restrict__ meta, int E){
    __shared__ int h[RNUM];
    int tid = threadIdx.x;
    if (tid < RNUM) h[tid] = 0;
    __syncthreads();
    int e = blockIdx.x * 256 + tid;
    if (e < E) atomicAdd(&h[etype[e]], 1);
    __syncthreads();
    if (tid < RNUM) atomicAdd(&meta[M_CNT + tid], h[tid]);
}

__global__ void k_offsets(int* __restrict__ meta){
    if (threadIdx.x == 0 && blockIdx.x == 0){
        int off = 0, blk = 0;
        meta[M_OFF] = 0; meta[M_BLK] = 0;
        for (int r = 0; r < RNUM; r++){
            int c = meta[M_CNT + r];
            off += c; blk += (c + BM - 1) / BM;
            meta[M_OFF + r + 1] = off;
            meta[M_BLK + r + 1] = blk;
            meta[M_CUR + r] = 0;
        }
    }
}

__global__ void k_scatter(const int* __restrict__ etype, int* __restrict__ meta,
                          int* __restrict__ perm, int E){
    __shared__ int lcnt[RNUM], lbase[RNUM];
    int tid = threadIdx.x;
    if (tid < RNUM) lcnt[tid] = 0;
    __syncthreads();
    int e = blockIdx.x * 256 + tid;
    int r = 0, rank = 0;
    if (e < E){ r = etype[e]; rank = atomicAdd(&lcnt[r], 1); }
    __syncthreads();
    if (tid < RNUM) lbase[tid] = atomicAdd(&meta[M_CUR + tid], lcnt[tid]);
    __syncthreads();
    if (e < E) perm[meta[M_OFF + r] + lbase[r] + rank] = e;
}

// =================== MFMA GEMM kernels ===================
// Shared tile plan: C-tile 128x128, 4 waves, wave w = rows [w*32,w*32+32).
// acc v4f [2 row-tiles][8 col-tiles]. K staged in 64-chunks (A,B 16KB each).
// Epilogue: bounce acc to f32 zbuf[64][132] in two 64-row passes.

#define ZP 132   // zbuf pitch (f32): 2-way bank conflicts only

// ---------------- k_x: x_bf = bf16(embs @ W_l + b_l) ----------------
__global__ __launch_bounds__(256, 3) void k_x_mfma(
    const unsigned short* __restrict__ embs_bf, const unsigned short* __restrict__ W_l_t,
    const float* __restrict__ b_l, unsigned short* __restrict__ x_bf, int N)
{
    __shared__ __align__(16) char smem[64 * ZP * 4];
    unsigned short* Ab = (unsigned short*)smem;
    unsigned short* Bb = (unsigned short*)(smem + 16384);
    float* zb = (float*)smem;

    const int tid = threadIdx.x;
    const int n0 = blockIdx.x * BM;
    const int cg = blockIdx.y;                // col group: cols [cg*128, +128)
    const int cnt = min(BM, N - n0);
    const int w = tid >> 6, lane = tid & 63, m = lane & 15, q = lane >> 4;

    v4f acc[2][8];
    #pragma unroll
    for (int i = 0; i < 2; i++)
        #pragma unroll
        for (int j = 0; j < 8; j++) acc[i][j] = 0.f;

    const int arow = tid >> 1;
    const long a_gr = (long)min(n0 + arow, N - 1) * D_DIM;
    const long b_gr = (long)(cg * BM + arow) * D_DIM;

    #pragma unroll
    for (int ch = 0; ch < 2; ch++){
        __syncthreads();
        stage64(Ab, embs_bf, a_gr + ch * 64, tid);
        stage64(Bb, W_l_t,   b_gr + ch * 64, tid);
        __syncthreads();
        #pragma unroll
        for (int ks = 0; ks < 2; ks++){
            v8s af[2], bf[8];
            #pragma unroll
            for (int rt = 0; rt < 2; rt++) af[rt] = frag_ld(Ab, w*32 + rt*16 + m, ks*4 + q);
            #pragma unroll
            for (int ct = 0; ct < 8; ct++) bf[ct] = frag_ld(Bb, ct*16 + m, ks*4 + q);
            #pragma unroll
            for (int rt = 0; rt < 2; rt++)
                #pragma unroll
                for (int ct = 0; ct < 8; ct++)
                    acc[rt][ct] = MFMA(af[rt], bf[ct], acc[rt][ct]);
        }
    }
    __syncthreads();

    for (int pp = 0; pp < 2; pp++){
        if ((w >> 1) == pp){
            int wr = (w & 1) * 32;
            #pragma unroll
            for (int rt = 0; rt < 2; rt++)
                #pragma unroll
                for (int ct = 0; ct < 8; ct++)
                    #pragma unroll
                    for (int g = 0; g < 4; g++)
                        zb[(wr + rt*16 + q*4 + g) * ZP + ct*16 + m] = acc[rt][ct][g];
        }
        __syncthreads();
        int rl = tid >> 2, pq = tid & 3;
        int row = pp * 64 + rl;
        if (row < cnt){
            const float* zp = zb + rl * ZP + pq * 32;
            const float* blp = b_l + cg * BM + pq * 32;
            long dst = (long)(n0 + row) * HC + cg * BM + pq * 32;
            #pragma unroll
            for (int g2 = 0; g2 < 4; g2++){
                us8 o;
                #pragma unroll
                for (int j = 0; j < 8; j++)
                    o[j] = f2bf(zp[g2*8 + j] + blp[g2*8 + j]);
                *(us8*)&x_bf[dst + g2*8] = o;
            }
        }
        __syncthreads();
    }
}

// ---------------- k_attr: edge_attr = bf16(gelu(concat(embs[s],embs[t]) @ rel[r])) ----------------
__global__ __launch_bounds__(256, 3) void k_attr_mfma(
    const unsigned short* __restrict__ embs_bf, const int* __restrict__ src, const int* __restrict__ trg,
    const unsigned short* __restrict__ rel_t, const int* __restrict__ perm, const int* __restrict__ meta,
    unsigned short* __restrict__ edge_attr)
{
    __shared__ __align__(16) char smem[64 * ZP * 4];
    unsigned short* Ab = (unsigned short*)smem;
    unsigned short* Bb = (unsigned short*)(smem + 16384);
    float* zb = (float*)smem;
    __shared__ int s_eid[BM], s_s[BM], s_t[BM];
    __shared__ int s_meta[3];

    const int tid = threadIdx.x;
    const int b = blockIdx.x;
    if (tid == 0){
        int nblk = meta[M_BLK + RNUM];
        if (b >= nblk){ s_meta[0] = -1; }
        else {
            int r = 0;
            while (b >= meta[M_BLK + r + 1]) r++;
            int chunk = b - meta[M_BLK + r];
            int base = meta[M_OFF + r] + chunk * BM;
            s_meta[0] = r; s_meta[1] = base;
            s_meta[2] = min(BM, meta[M_OFF + r + 1] - base);
        }
    }
    __syncthreads();
    const int r = s_meta[0];
    if (r < 0) return;
    const int base = s_meta[1], cnt = s_meta[2];
    if (tid < BM){
        int e = perm[base + min(tid, cnt - 1)];
        s_eid[tid] = e; s_s[tid] = src[e]; s_t[tid] = trg[e];
    }
    const int w = tid >> 6, lane = tid & 63, m = lane & 15, q = lane >> 4;

    v4f acc[2][8];
    #pragma unroll
    for (int i = 0; i < 2; i++)
        #pragma unroll
        for (int j = 0; j < 8; j++) acc[i][j] = 0.f;

    const int arow = tid >> 1;
    const long b_gr = ((long)r * BM + arow) * TWO_D;
    __syncthreads();   // s_eid/s_s/s_t visible

    #pragma unroll
    for (int ch = 0; ch < 4; ch++){
        __syncthreads();
        int node = (ch < 2) ? s_s[arow] : s_t[arow];
        stage64(Ab, embs_bf, (long)node * D_DIM + (ch & 1) * 64, tid);
        stage64(Bb, rel_t,   b_gr + ch * 64, tid);
        __syncthreads();
        #pragma unroll
        for (int ks = 0; ks < 2; ks++){
            v8s af[2], bf[8];
            #pragma unroll
            for (int rt = 0; rt < 2; rt++) af[rt] = frag_ld(Ab, w*32 + rt*16 + m, ks*4 + q);
            #pragma unroll
            for (int ct = 0; ct < 8; ct++) bf[ct] = frag_ld(Bb, ct*16 + m, ks*4 + q);
            #pragma unroll
            for (int rt = 0; rt < 2; rt++)
                #pragma unroll
                for (int ct = 0; ct < 8; ct++)
                    acc[rt][ct] = MFMA(af[rt], bf[ct], acc[rt][ct]);
        }
    }
    __syncthreads();

    for (int pp = 0; pp < 2; pp++){
        if ((w >> 1) == pp){
            int wr = (w & 1) * 32;
            #pragma unroll
            for (int rt = 0; rt < 2; rt++)
                #pragma unroll
                for (int ct = 0; ct < 8; ct++)
                    #pragma unroll
                    for (int g = 0; g < 4; g++)
                        zb[(wr + rt*16 + q*4 + g) * ZP + ct*16 + m] = acc[rt][ct][g];
        }
        __syncthreads();
        int rl = tid >> 2, pq = tid & 3;
        int row = pp * 64 + rl;
        if (row < cnt){
            const float* zp = zb + rl * ZP + pq * 32;
            long dst = (long)s_eid[row] * D_DIM + pq * 32;
            #pragma unroll
            for (int g2 = 0; g2 < 4; g2++){
                us8 o;
                #pragma unroll
                for (int j = 0; j < 8; j++){
                    float v = zp[g2*8 + j];
                    v = 0.5f * v * (1.f + erff(v * 0.70710678118654752f));
                    o[j] = f2bf(v);
                }
                *(us8*)&edge_attr[dst + g2*8] = o;
            }
        }
        __syncthreads();
    }
}

// ---------------- k_logits: z=lrelu(x_i+x_j+edge_attr@W_e); logits=z.att ----------------
__global__ __launch_bounds__(256, 3) void k_logits_mfma(
    const unsigned short* __restrict__ edge_attr, const unsigned short* __restrict__ W_e_t,
    const float* __restrict__ att, const unsigned short* __restrict__ x_bf,
    const int* __restrict__ src, const int* __restrict__ trg,
    float* __restrict__ logits, unsigned* __restrict__ node_max, int E)
{
    __shared__ __align__(16) char smem[64 * ZP * 4];
    unsigned short* Ab = (unsigned short*)smem;
    unsigned short* Bb = (unsigned short*)(smem + 16384);
    float* zb = (float*)smem;
    __shared__ int s_s[BM], s_t[BM];

    const int tid = threadIdx.x;
    const int e0 = blockIdx.x * BM;
    const int h = blockIdx.y;
    const int cnt = min(BM, E - e0);
    if (tid < BM){
        int e = e0 + min(tid, cnt - 1);
        s_s[tid] = src[e]; s_t[tid] = trg[e];
    }
    const int w = tid >> 6, lane = tid & 63, m = lane & 15, q = lane >> 4;

    v4f acc[2][8];
    #pragma unroll
    for (int i = 0; i < 2; i++)
        #pragma unroll
        for (int j = 0; j < 8; j++) acc[i][j] = 0.f;

    const int arow = tid >> 1;
    const long a_gr = (long)(e0 + min(arow, cnt - 1)) * D_DIM;
    const long b_gr = (long)(h * BM + arow) * D_DIM;

    #pragma unroll
    for (int ch = 0; ch < 2; ch++){
        __syncthreads();
        stage64(Ab, edge_attr, a_gr + ch * 64, tid);
        stage64(Bb, W_e_t,     b_gr + ch * 64, tid);
        __syncthreads();
        #pragma unroll
        for (int ks = 0; ks < 2; ks++){
            v8s af[2], bf[8];
            #pragma unroll
            for (int rt = 0; rt < 2; rt++) af[rt] = frag_ld(Ab, w*32 + rt*16 + m, ks*4 + q);
            #pragma unroll
            for (int ct = 0; ct < 8; ct++) bf[ct] = frag_ld(Bb, ct*16 + m, ks*4 + q);
            #pragma unroll
            for (int rt = 0; rt < 2; rt++)
                #pragma unroll
                for (int ct = 0; ct < 8; ct++)
                    acc[rt][ct] = MFMA(af[rt], bf[ct], acc[rt][ct]);
        }
    }
    __syncthreads();

    for (int pp = 0; pp < 2; pp++){
        if ((w >> 1) == pp){
            int wr = (w & 1) * 32;
            #pragma unroll
            for (int rt = 0; rt < 2; rt++)
                #pragma unroll
                for (int ct = 0; ct < 8; ct++)
                    #pragma unroll
                    for (int g = 0; g < 4; g++)
                        zb[(wr + rt*16 + q*4 + g) * ZP + ct*16 + m] = acc[rt][ct][g];
        }
        __syncthreads();
        int rl = tid >> 2, pq = tid & 3;
        int row = pp * 64 + rl;
        float part = 0.f;
        if (row < cnt){
            int s = s_s[row], t = s_t[row];
            const float* zp = zb + rl * ZP + pq * 32;
            const unsigned short* xip = x_bf + (long)t * HC + h * BM + pq * 32;
            const unsigned short* xjp = x_bf + (long)s * HC + h * BM + pq * 32;
            const float* ap = att + h * BM + pq * 32;
            #pragma unroll
            for (int g2 = 0; g2 < 4; g2++){
                us8 xi = *(const us8*)(xip + g2*8);
                us8 xj = *(const us8*)(xjp + g2*8);
                #pragma unroll
                for (int j = 0; j < 8; j++){
                    float z = zp[g2*8 + j] + bf2f(xi[j]) + bf2f(xj[j]);
                    z = (z > 0.f) ? z : 0.2f * z;
                    part += z * ap[g2*8 + j];
                }
            }
        }
        part += __shfl_xor(part, 1, 64);
        part += __shfl_xor(part, 2, 64);
        if ((tid & 3) == 0 && row < cnt){
            logits[(long)(e0 + row) * NH + h] = part;
            atomicMax(&node_max[(long)s_t[row] * NH + h], ford(part));
        }
        __syncthreads();
    }
}

// ---------------- softmax pieces ----------------
__global__ void k_softmax(float* __restrict__ logits, const int* __restrict__ trg,
                          const unsigned* __restrict__ node_max, float* __restrict__ node_sum,
                          int E){
    long total = (long)E * NH;
    long i = (long)blockIdx.x * blockDim.x + threadIdx.x;
    if (i >= total) return;
    int e = (int)(i >> 2), hh = (int)(i & 3);
    int t = trg[e];
    float m = funord(node_max[(long)t * NH + hh]);
    float ex = expf(logits[i] - m);
    logits[i] = ex;
    atomicAdd(&node_sum[(long)t * NH + hh], ex);
}

// ---------------- aggregation ----------------
__global__ __launch_bounds__(128) void k_agg(const float* __restrict__ ex,
                                             const float* __restrict__ node_sum,
                                             const unsigned short* __restrict__ x_bf,
                                             const int* __restrict__ src,
                                             const int* __restrict__ trg,
                                             float* __restrict__ out, int E){
    const int e = blockIdx.x;
    if (e >= E) return;
    const int tid = threadIdx.x;
    const int s = src[e], t = trg[e];
    __shared__ float a[NH];
    if (tid < NH){
        float sum = node_sum[(long)t * NH + tid];
        a[tid] = ex[(long)e * NH + tid] / fmaxf(sum, 1e-16f);
    }
    __syncthreads();
    #pragma unroll
    for (int u = 0; u < 4; u++){
        int c = tid + u * 128;
        float xv = bf2f(x_bf[(long)s * HC + c]);
        atomicAdd(&out[(long)t * HC + c], xv * a[c >> 7]);
    }
}

extern "C" void kernel_launch(void* const* d_in, const int* in_sizes, int n_in,
                              void* d_out, int out_size, void* d_ws, size_t ws_size,
                              hipStream_t stream) {
    const float* embs       = (const float*)d_in[0];
    const int*   edge_index = (const int*)  d_in[1];
    const int*   etype      = (const int*)  d_in[2];
    const float* rel        = (const float*)d_in[3];
    const float* W_l        = (const float*)d_in[4];
    const float* b_l        = (const float*)d_in[5];
    const float* W_e        = (const float*)d_in[6];
    const float* att        = (const float*)d_in[7];
    const float* bias       = (const float*)d_in[8];

    const int N = in_sizes[0] / D_DIM;
    const int E = in_sizes[1] / 2;
    const int* src = edge_index;
    const int* trg = edge_index + E;

    char* ws = (char*)d_ws;
    size_t off = 0;
    unsigned short* x_bf = (unsigned short*)(ws + off);      off += (size_t)N * HC * 2;
    unsigned short* embs_bf = (unsigned short*)(ws + off);   off += (size_t)N * D_DIM * 2;
    unsigned short* edge_attr = (unsigned short*)(ws + off); off += (size_t)E * D_DIM * 2;
    unsigned short* rel_t = (unsigned short*)(ws + off);     off += (size_t)RNUM * D_DIM * TWO_D * 2;
    unsigned short* W_e_t = (unsigned short*)(ws + off);     off += (size_t)HC * D_DIM * 2;
    unsigned short* W_l_t = (unsigned short*)(ws + off);     off += (size_t)HC * D_DIM * 2;
    float* logits = (float*)(ws + off);                      off += (size_t)E * NH * 4;
    unsigned* node_max = (unsigned*)(ws + off);              off += (size_t)N * NH * 4;
    float* node_sum = (float*)(ws + off);                    off += (size_t)N * NH * 4;
    int* perm = (int*)(ws + off);                            off += (size_t)E * 4;
    int* meta = (int*)(ws + off);                            off += 64 * 4;

    float* out = (float*)d_out;

    const int eb = (E + 255) / 256;
    const int ab = (E + BM - 1) / BM + RNUM;
    const int lb = (E + BM - 1) / BM;

    k_init<<<2048, 256, 0, stream>>>(out, bias, node_max, node_sum, meta, N);
    k_prep<<<2048, 256, 0, stream>>>(embs, rel, W_e, W_l, embs_bf, rel_t, W_e_t, W_l_t, N);
    k_hist<<<eb, 256, 0, stream>>>(etype, meta, E);
    k_offsets<<<1, 64, 0, stream>>>(meta);
    k_scatter<<<eb, 256, 0, stream>>>(etype, meta, perm, E);
    k_x_mfma<<<dim3((N + BM - 1) / BM, NH), 256, 0, stream>>>(embs_bf, W_l_t, b_l, x_bf, N);
    k_attr_mfma<<<ab, 256, 0, stream>>>(embs_bf, src, trg, rel_t, perm, meta, edge_attr);
    k_logits_mfma<<<dim3(lb, NH), 256, 0, stream>>>(edge_attr, W_e_t, att, x_bf, src, trg, logits, node_max, E);
    k_softmax<<<(int)(((long)E * NH + 255) / 256), 256, 0, stream>>>(logits, trg, node_max, node_sum, E);
    k_agg<<<E, 128, 0, stream>>>(logits, node_sum, x_bf, src, trg, out, E);
}

// Round 5
// 568.381 us; speedup vs baseline: 5.2807x; 1.2556x over previous
//
#include <hip/hip_runtime.h>
#include <math.h>

#define D_DIM 128
#define TWO_D 256
#define HC    512
#define NH    4
#define RNUM  8
#define BM    128

#define M_CNT 0
#define M_OFF 8
#define M_BLK 17
#define M_CUR 26

typedef __attribute__((ext_vector_type(8))) short v8s;
typedef __attribute__((ext_vector_type(4))) float v4f;
typedef __attribute__((ext_vector_type(8))) unsigned short us8;

#define MFMA(a,b,c) __builtin_amdgcn_mfma_f32_16x16x32_bf16((a),(b),(c),0,0,0)

__device__ __forceinline__ float bf2f(unsigned short v){
    return __uint_as_float(((unsigned)v) << 16);
}
__device__ __forceinline__ unsigned short f2bf(float f){
    unsigned u = __float_as_uint(f);
    u += 0x7fffu + ((u >> 16) & 1u);
    return (unsigned short)(u >> 16);
}

// ---- LDS swizzled tile helpers ----
__device__ __forceinline__ unsigned short* tile_ptr(unsigned short* buf, int r, int chunk){
    return buf + r * 64 + ((chunk ^ (r & 7)) << 3);
}
__device__ __forceinline__ v8s frag_ld(const unsigned short* buf, int r, int chunk){
    return *(const v8s*)(buf + r * 64 + ((chunk ^ (r & 7)) << 3));
}
__device__ __forceinline__ void stage64(unsigned short* lds, const unsigned short* gbase,
                                        long roff, int tid){
    int r = tid >> 1, p = tid & 1;
    const unsigned short* src = gbase + roff + p * 32;
    #pragma unroll
    for (int i = 0; i < 4; i++){
        int c = p * 4 + i;
        uint4 v = *(const uint4*)(src + i * 8);
        *(uint4*)tile_ptr(lds, r, c) = v;
    }
}

// ---------------- init: meta + per-target counters ----------------
__global__ void k_init(int* __restrict__ meta, int* __restrict__ tcnt,
                       int* __restrict__ tcur, int N){
    int i = blockIdx.x * 256 + threadIdx.x;
    if (i < N){ tcnt[i] = 0; tcur[i] = 0; }
    if (i < RNUM) meta[M_CNT + i] = 0;
}

// ---------------- prep: bf16 conversions + B-operand transposes ----------------
__global__ void k_prep(const float* __restrict__ embs, const float* __restrict__ rel,
                       const float* __restrict__ W_e, const float* __restrict__ W_l,
                       unsigned short* __restrict__ embs_bf, unsigned short* __restrict__ rel_t,
                       unsigned short* __restrict__ W_e_t, unsigned short* __restrict__ W_l_t, int N){
    const long T0 = (long)N * D_DIM;
    const long T1 = T0 + (long)RNUM * D_DIM * TWO_D;
    const long T2 = T1 + (long)HC * D_DIM;
    const long T3 = T2 + (long)HC * D_DIM;
    long stride = (long)gridDim.x * blockDim.x;
    for (long i = (long)blockIdx.x * blockDim.x + threadIdx.x; i < T3; i += stride){
        if (i < T0){
            embs_bf[i] = f2bf(embs[i]);
        } else if (i < T1){
            long j = i - T0;
            int r = (int)(j >> 15);
            int rem = (int)(j & 32767);
            int n = rem >> 8, k = rem & 255;
            rel_t[j] = f2bf(rel[(long)r * 32768 + (long)k * D_DIM + n]);
        } else if (i < T2){
            long j = i - T1;
            int n = (int)(j >> 7), k = (int)(j & 127);
            W_e_t[j] = f2bf(W_e[(long)k * HC + n]);
        } else {
            long j = i - T2;
            int n = (int)(j >> 7), k = (int)(j & 127);
            W_l_t[j] = f2bf(W_l[(long)k * HC + n]);
        }
    }
}

// ---------------- relation bucketing ----------------
__global__ void k_hist(const int* __restrict__ etype, int* __restrict__ meta, int E){
    __shared__ int h[RNUM];
    int tid = threadIdx.x;
    if (tid < RNUM) h[tid] = 0;
    __syncthreads();
    int e = blockIdx.x * 256 + tid;
    if (e < E) atomicAdd(&h[etype[e]], 1);
    __syncthreads();
    if (tid < RNUM) atomicAdd(&meta[M_CNT + tid], h[tid]);
}

__global__ void k_offsets(int* __restrict__ meta){
    if (threadIdx.x == 0 && blockIdx.x == 0){
        int off = 0, blk = 0;
        meta[M_OFF] = 0; meta[M_BLK] = 0;
        for (int r = 0; r < RNUM; r++){
            int c = meta[M_CNT + r];
            off += c; blk += (c + BM - 1) / BM;
            meta[M_OFF + r + 1] = off;
            meta[M_BLK + r + 1] = blk;
            meta[M_CUR + r] = 0;
        }
    }
}

__global__ void k_scatter(const int* __restrict__ etype, int* __restrict__ meta,
                          int* __restrict__ perm, int E){
    __shared__ int lcnt[RNUM], lbase[RNUM];
    int tid = threadIdx.x;
    if (tid < RNUM) lcnt[tid] = 0;
    __syncthreads();
    int e = blockIdx.x * 256 + tid;
    int r = 0, rank = 0;
    if (e < E){ r = etype[e]; rank = atomicAdd(&lcnt[r], 1); }
    __syncthreads();
    if (tid < RNUM) lbase[tid] = atomicAdd(&meta[M_CUR + tid], lcnt[tid]);
    __syncthreads();
    if (e < E) perm[meta[M_OFF + r] + lbase[r] + rank] = e;
}

// ---------------- target-CSR build ----------------
__global__ void k_tcnt(const int* __restrict__ trg, int* __restrict__ tcnt, int E){
    int e = blockIdx.x * 256 + threadIdx.x;
    if (e < E) atomicAdd(&tcnt[trg[e]], 1);
}

__global__ __launch_bounds__(1024) void k_tscan(const int* __restrict__ tcnt,
                                                int* __restrict__ rowptr, int N){
    __shared__ int part[1024];
    const int T = 1024;
    int tid = threadIdx.x;
    int chunk = (N + T - 1) / T;
    int lo = tid * chunk, hi = min(lo + chunk, N);
    int s = 0;
    for (int i = lo; i < hi; i++) s += tcnt[i];
    part[tid] = s;
    __syncthreads();
    for (int off = 1; off < T; off <<= 1){
        int v = (tid >= off) ? part[tid - off] : 0;
        __syncthreads();
        part[tid] += v;
        __syncthreads();
    }
    int run = (tid == 0) ? 0 : part[tid - 1];
    for (int i = lo; i < hi; i++){ rowptr[i] = run; run += tcnt[i]; }
    if (tid == T - 1) rowptr[N] = part[T - 1];
}

__global__ void k_tscatter(const int* __restrict__ trg, const int* __restrict__ rowptr,
                           int* __restrict__ tcur, int* __restrict__ eidx, int E){
    int e = blockIdx.x * 256 + threadIdx.x;
    if (e < E){
        int t = trg[e];
        int pos = rowptr[t] + atomicAdd(&tcur[t], 1);
        eidx[pos] = e;
    }
}

// =================== MFMA GEMM kernels ===================
#define ZP 132

// ---------------- k_x: x_bf = bf16(embs @ W_l + b_l) ----------------
__global__ __launch_bounds__(256, 3) void k_x_mfma(
    const unsigned short* __restrict__ embs_bf, const unsigned short* __restrict__ W_l_t,
    const float* __restrict__ b_l, unsigned short* __restrict__ x_bf, int N)
{
    __shared__ __align__(16) char smem[64 * ZP * 4];
    unsigned short* Ab = (unsigned short*)smem;
    unsigned short* Bb = (unsigned short*)(smem + 16384);
    float* zb = (float*)smem;

    const int tid = threadIdx.x;
    const int n0 = blockIdx.x * BM;
    const int cg = blockIdx.y;
    const int cnt = min(BM, N - n0);
    const int w = tid >> 6, lane = tid & 63, m = lane & 15, q = lane >> 4;

    v4f acc[2][8];
    #pragma unroll
    for (int i = 0; i < 2; i++)
        #pragma unroll
        for (int j = 0; j < 8; j++) acc[i][j] = 0.f;

    const int arow = tid >> 1;
    const long a_gr = (long)min(n0 + arow, N - 1) * D_DIM;
    const long b_gr = (long)(cg * BM + arow) * D_DIM;

    #pragma unroll
    for (int ch = 0; ch < 2; ch++){
        __syncthreads();
        stage64(Ab, embs_bf, a_gr + ch * 64, tid);
        stage64(Bb, W_l_t,   b_gr + ch * 64, tid);
        __syncthreads();
        #pragma unroll
        for (int ks = 0; ks < 2; ks++){
            v8s af[2], bf[8];
            #pragma unroll
            for (int rt = 0; rt < 2; rt++) af[rt] = frag_ld(Ab, w*32 + rt*16 + m, ks*4 + q);
            #pragma unroll
            for (int ct = 0; ct < 8; ct++) bf[ct] = frag_ld(Bb, ct*16 + m, ks*4 + q);
            #pragma unroll
            for (int rt = 0; rt < 2; rt++)
                #pragma unroll
                for (int ct = 0; ct < 8; ct++)
                    acc[rt][ct] = MFMA(af[rt], bf[ct], acc[rt][ct]);
        }
    }
    __syncthreads();

    for (int pp = 0; pp < 2; pp++){
        if ((w >> 1) == pp){
            int wr = (w & 1) * 32;
            #pragma unroll
            for (int rt = 0; rt < 2; rt++)
                #pragma unroll
                for (int ct = 0; ct < 8; ct++)
                    #pragma unroll
                    for (int g = 0; g < 4; g++)
                        zb[(wr + rt*16 + q*4 + g) * ZP + ct*16 + m] = acc[rt][ct][g];
        }
        __syncthreads();
        int rl = tid >> 2, pq = tid & 3;
        int row = pp * 64 + rl;
        if (row < cnt){
            const float* zp = zb + rl * ZP + pq * 32;
            const float* blp = b_l + cg * BM + pq * 32;
            long dst = (long)(n0 + row) * HC + cg * BM + pq * 32;
            #pragma unroll
            for (int g2 = 0; g2 < 4; g2++){
                us8 o;
                #pragma unroll
                for (int j = 0; j < 8; j++)
                    o[j] = f2bf(zp[g2*8 + j] + blp[g2*8 + j]);
                *(us8*)&x_bf[dst + g2*8] = o;
            }
        }
        __syncthreads();
    }
}

// ---------------- k_attr ----------------
__global__ __launch_bounds__(256, 3) void k_attr_mfma(
    const unsigned short* __restrict__ embs_bf, const int* __restrict__ src, const int* __restrict__ trg,
    const unsigned short* __restrict__ rel_t, const int* __restrict__ perm, const int* __restrict__ meta,
    unsigned short* __restrict__ edge_attr)
{
    __shared__ __align__(16) char smem[64 * ZP * 4];
    unsigned short* Ab = (unsigned short*)smem;
    unsigned short* Bb = (unsigned short*)(smem + 16384);
    float* zb = (float*)smem;
    __shared__ int s_eid[BM], s_s[BM], s_t[BM];
    __shared__ int s_meta[3];

    const int tid = threadIdx.x;
    const int b = blockIdx.x;
    if (tid == 0){
        int nblk = meta[M_BLK + RNUM];
        if (b >= nblk){ s_meta[0] = -1; }
        else {
            int r = 0;
            while (b >= meta[M_BLK + r + 1]) r++;
            int chunk = b - meta[M_BLK + r];
            int base = meta[M_OFF + r] + chunk * BM;
            s_meta[0] = r; s_meta[1] = base;
            s_meta[2] = min(BM, meta[M_OFF + r + 1] - base);
        }
    }
    __syncthreads();
    const int r = s_meta[0];
    if (r < 0) return;
    const int base = s_meta[1], cnt = s_meta[2];
    if (tid < BM){
        int e = perm[base + min(tid, cnt - 1)];
        s_eid[tid] = e; s_s[tid] = src[e]; s_t[tid] = trg[e];
    }
    const int w = tid >> 6, lane = tid & 63, m = lane & 15, q = lane >> 4;

    v4f acc[2][8];
    #pragma unroll
    for (int i = 0; i < 2; i++)
        #pragma unroll
        for (int j = 0; j < 8; j++) acc[i][j] = 0.f;

    const int arow = tid >> 1;
    const long b_gr = ((long)r * BM + arow) * TWO_D;
    __syncthreads();

    #pragma unroll
    for (int ch = 0; ch < 4; ch++){
        __syncthreads();
        int node = (ch < 2) ? s_s[arow] : s_t[arow];
        stage64(Ab, embs_bf, (long)node * D_DIM + (ch & 1) * 64, tid);
        stage64(Bb, rel_t,   b_gr + ch * 64, tid);
        __syncthreads();
        #pragma unroll
        for (int ks = 0; ks < 2; ks++){
            v8s af[2], bf[8];
            #pragma unroll
            for (int rt = 0; rt < 2; rt++) af[rt] = frag_ld(Ab, w*32 + rt*16 + m, ks*4 + q);
            #pragma unroll
            for (int ct = 0; ct < 8; ct++) bf[ct] = frag_ld(Bb, ct*16 + m, ks*4 + q);
            #pragma unroll
            for (int rt = 0; rt < 2; rt++)
                #pragma unroll
                for (int ct = 0; ct < 8; ct++)
                    acc[rt][ct] = MFMA(af[rt], bf[ct], acc[rt][ct]);
        }
    }
    __syncthreads();

    for (int pp = 0; pp < 2; pp++){
        if ((w >> 1) == pp){
            int wr = (w & 1) * 32;
            #pragma unroll
            for (int rt = 0; rt < 2; rt++)
                #pragma unroll
                for (int ct = 0; ct < 8; ct++)
                    #pragma unroll
                    for (int g = 0; g < 4; g++)
                        zb[(wr + rt*16 + q*4 + g) * ZP + ct*16 + m] = acc[rt][ct][g];
        }
        __syncthreads();
        int rl = tid >> 2, pq = tid & 3;
        int row = pp * 64 + rl;
        if (row < cnt){
            const float* zp = zb + rl * ZP + pq * 32;
            long dst = (long)s_eid[row] * D_DIM + pq * 32;
            #pragma unroll
            for (int g2 = 0; g2 < 4; g2++){
                us8 o;
                #pragma unroll
                for (int j = 0; j < 8; j++){
                    float v = zp[g2*8 + j];
                    v = 0.5f * v * (1.f + erff(v * 0.70710678118654752f));
                    o[j] = f2bf(v);
                }
                *(us8*)&edge_attr[dst + g2*8] = o;
            }
        }
        __syncthreads();
    }
}

// ---------------- k_logits (no atomics; raw logits only) ----------------
__global__ __launch_bounds__(256, 3) void k_logits_mfma(
    const unsigned short* __restrict__ edge_attr, const unsigned short* __restrict__ W_e_t,
    const float* __restrict__ att, const unsigned short* __restrict__ x_bf,
    const int* __restrict__ src, const int* __restrict__ trg,
    float* __restrict__ logits, int E)
{
    __shared__ __align__(16) char smem[64 * ZP * 4];
    unsigned short* Ab = (unsigned short*)smem;
    unsigned short* Bb = (unsigned short*)(smem + 16384);
    float* zb = (float*)smem;
    __shared__ int s_s[BM], s_t[BM];

    const int tid = threadIdx.x;
    const int e0 = blockIdx.x * BM;
    const int h = blockIdx.y;
    const int cnt = min(BM, E - e0);
    if (tid < BM){
        int e = e0 + min(tid, cnt - 1);
        s_s[tid] = src[e]; s_t[tid] = trg[e];
    }
    const int w = tid >> 6, lane = tid & 63, m = lane & 15, q = lane >> 4;

    v4f acc[2][8];
    #pragma unroll
    for (int i = 0; i < 2; i++)
        #pragma unroll
        for (int j = 0; j < 8; j++) acc[i][j] = 0.f;

    const int arow = tid >> 1;
    const long a_gr = (long)(e0 + min(arow, cnt - 1)) * D_DIM;
    const long b_gr = (long)(h * BM + arow) * D_DIM;

    #pragma unroll
    for (int ch = 0; ch < 2; ch++){
        __syncthreads();
        stage64(Ab, edge_attr, a_gr + ch * 64, tid);
        stage64(Bb, W_e_t,     b_gr + ch * 64, tid);
        __syncthreads();
        #pragma unroll
        for (int ks = 0; ks < 2; ks++){
            v8s af[2], bf[8];
            #pragma unroll
            for (int rt = 0; rt < 2; rt++) af[rt] = frag_ld(Ab, w*32 + rt*16 + m, ks*4 + q);
            #pragma unroll
            for (int ct = 0; ct < 8; ct++) bf[ct] = frag_ld(Bb, ct*16 + m, ks*4 + q);
            #pragma unroll
            for (int rt = 0; rt < 2; rt++)
                #pragma unroll
                for (int ct = 0; ct < 8; ct++)
                    acc[rt][ct] = MFMA(af[rt], bf[ct], acc[rt][ct]);
        }
    }
    __syncthreads();

    for (int pp = 0; pp < 2; pp++){
        if ((w >> 1) == pp){
            int wr = (w & 1) * 32;
            #pragma unroll
            for (int rt = 0; rt < 2; rt++)
                #pragma unroll
                for (int ct = 0; ct < 8; ct++)
                    #pragma unroll
                    for (int g = 0; g < 4; g++)
                        zb[(wr + rt*16 + q*4 + g) * ZP + ct*16 + m] = acc[rt][ct][g];
        }
        __syncthreads();
        int rl = tid >> 2, pq = tid & 3;
        int row = pp * 64 + rl;
        float part = 0.f;
        if (row < cnt){
            int s = s_s[row], t = s_t[row];
            const float* zp = zb + rl * ZP + pq * 32;
            const unsigned short* xip = x_bf + (long)t * HC + h * BM + pq * 32;
            const unsigned short* xjp = x_bf + (long)s * HC + h * BM + pq * 32;
            const float* ap = att + h * BM + pq * 32;
            #pragma unroll
            for (int g2 = 0; g2 < 4; g2++){
                us8 xi = *(const us8*)(xip + g2*8);
                us8 xj = *(const us8*)(xjp + g2*8);
                #pragma unroll
                for (int j = 0; j < 8; j++){
                    float z = zp[g2*8 + j] + bf2f(xi[j]) + bf2f(xj[j]);
                    z = (z > 0.f) ? z : 0.2f * z;
                    part += z * ap[g2*8 + j];
                }
            }
        }
        part += __shfl_xor(part, 1, 64);
        part += __shfl_xor(part, 2, 64);
        if ((tid & 3) == 0 && row < cnt)
            logits[(long)(e0 + row) * NH + h] = part;
        __syncthreads();
    }
}

// ---------------- CSR aggregation: one wave per target node ----------------
__global__ __launch_bounds__(256) void k_agg_csr(
    const float* __restrict__ logits, const int* __restrict__ rowptr,
    const int* __restrict__ eidx, const int* __restrict__ src,
    const unsigned short* __restrict__ x_bf, const float* __restrict__ bias,
    float* __restrict__ out, int N)
{
    int t = blockIdx.x * 4 + (threadIdx.x >> 6);
    if (t >= N) return;
    int lane = threadIdx.x & 63;
    int c0 = lane * 8;
    int h = lane >> 4;                   // head for my 8 cols
    int lo = rowptr[t], hi = rowptr[t + 1];

    float acc[8];
    #pragma unroll
    for (int j = 0; j < 8; j++) acc[j] = bias[c0 + j];

    if (lo < hi){
        float mx = -3.0e38f;
        for (int i = lo; i < hi; i++){
            float4 lg = *(const float4*)&logits[(long)eidx[i] * NH];
            float l = (h == 0) ? lg.x : (h == 1) ? lg.y : (h == 2) ? lg.z : lg.w;
            mx = fmaxf(mx, l);
        }
        float ssum = 0.f;
        for (int i = lo; i < hi; i++){
            float4 lg = *(const float4*)&logits[(long)eidx[i] * NH];
            float l = (h == 0) ? lg.x : (h == 1) ? lg.y : (h == 2) ? lg.z : lg.w;
            ssum += expf(l - mx);
        }
        float inv = 1.f / fmaxf(ssum, 1e-16f);
        for (int i = lo; i < hi; i++){
            int e = eidx[i];
            float4 lg = *(const float4*)&logits[(long)e * NH];
            float l = (h == 0) ? lg.x : (h == 1) ? lg.y : (h == 2) ? lg.z : lg.w;
            float alpha = expf(l - mx) * inv;
            us8 xv = *(const us8*)&x_bf[(long)src[e] * HC + c0];
            #pragma unroll
            for (int j = 0; j < 8; j++) acc[j] += alpha * bf2f(xv[j]);
        }
    }
    long dst = (long)t * HC + c0;
    *(float4*)&out[dst]     = make_float4(acc[0], acc[1], acc[2], acc[3]);
    *(float4*)&out[dst + 4] = make_float4(acc[4], acc[5], acc[6], acc[7]);
}

extern "C" void kernel_launch(void* const* d_in, const int* in_sizes, int n_in,
                              void* d_out, int out_size, void* d_ws, size_t ws_size,
                              hipStream_t stream) {
    const float* embs       = (const float*)d_in[0];
    const int*   edge_index = (const int*)  d_in[1];
    const int*   etype      = (const int*)  d_in[2];
    const float* rel        = (const float*)d_in[3];
    const float* W_l        = (const float*)d_in[4];
    const float* b_l        = (const float*)d_in[5];
    const float* W_e        = (const float*)d_in[6];
    const float* att        = (const float*)d_in[7];
    const float* bias       = (const float*)d_in[8];

    const int N = in_sizes[0] / D_DIM;
    const int E = in_sizes[1] / 2;
    const int* src = edge_index;
    const int* trg = edge_index + E;

    char* ws = (char*)d_ws;
    size_t off = 0;
    unsigned short* x_bf = (unsigned short*)(ws + off);      off += (size_t)N * HC * 2;
    unsigned short* embs_bf = (unsigned short*)(ws + off);   off += (size_t)N * D_DIM * 2;
    unsigned short* edge_attr = (unsigned short*)(ws + off); off += (size_t)E * D_DIM * 2;
    unsigned short* rel_t = (unsigned short*)(ws + off);     off += (size_t)RNUM * D_DIM * TWO_D * 2;
    unsigned short* W_e_t = (unsigned short*)(ws + off);     off += (size_t)HC * D_DIM * 2;
    unsigned short* W_l_t = (unsigned short*)(ws + off);     off += (size_t)HC * D_DIM * 2;
    float* logits = (float*)(ws + off);                      off += (size_t)E * NH * 4;
    int* perm = (int*)(ws + off);                            off += (size_t)E * 4;
    int* meta = (int*)(ws + off);                            off += 64 * 4;
    int* tcnt = (int*)(ws + off);                            off += (size_t)N * 4;
    int* tcur = (int*)(ws + off);                            off += (size_t)N * 4;
    int* rowptr = (int*)(ws + off);                          off += (size_t)(N + 1) * 4;
    int* eidx = (int*)(ws + off);                            off += (size_t)E * 4;

    float* out = (float*)d_out;

    const int eb = (E + 255) / 256;
    const int nb = (N + 255) / 256;
    const int ab = (E + BM - 1) / BM + RNUM;
    const int lb = (E + BM - 1) / BM;

    k_init<<<nb, 256, 0, stream>>>(meta, tcnt, tcur, N);
    k_prep<<<2048, 256, 0, stream>>>(embs, rel, W_e, W_l, embs_bf, rel_t, W_e_t, W_l_t, N);
    k_hist<<<eb, 256, 0, stream>>>(etype, meta, E);
    k_offsets<<<1, 64, 0, stream>>>(meta);
    k_scatter<<<eb, 256, 0, stream>>>(etype, meta, perm, E);
    k_tcnt<<<eb, 256, 0, stream>>>(trg, tcnt, E);
    k_tscan<<<1, 1024, 0, stream>>>(tcnt, rowptr, N);
    k_tscatter<<<eb, 256, 0, stream>>>(trg, rowptr, tcur, eidx, E);
    k_x_mfma<<<dim3((N + BM - 1) / BM, NH), 256, 0, stream>>>(embs_bf, W_l_t, b_l, x_bf, N);
    k_attr_mfma<<<ab, 256, 0, stream>>>(embs_bf, src, trg, rel_t, perm, meta, edge_attr);
    k_logits_mfma<<<dim3(lb, NH), 256, 0, stream>>>(edge_attr, W_e_t, att, x_bf, src, trg, logits, E);
    k_agg_csr<<<(N + 3) / 4, 256, 0, stream>>>(logits, rowptr, eidx, src, x_bf, bias, out, N);
}